// Round 3
// baseline (277.820 us; speedup 1.0000x reference)
//
#include <hip/hip_runtime.h>
#include <math.h>

#define N_SYM 128
#define BATCH 131072
#define LEV   30.0f
#define PF    8   // prefetch depth: 4 streams x 8 deep = 32 pending dwords/lane

// One thread per batch column; sequential 128-symbol scan (unused-margin
// carry). Occupancy is grid-capped at 2 waves/SIMD (131072 lanes / 256 CUs),
// so latency hiding must come from per-lane MLP. KEY: __launch_bounds__(256,2)
// tells the scheduler the true occupancy target, unlocking ~256 VGPRs so it
// keeps the PF-deep prefetch ring's loads hoisted (32 dwords/lane in flight)
// instead of sinking them to their uses under a 64-VGPR budget (which is what
// capped R1/R2 at ~4 dwords/lane -> 1.7 TB/s).
__global__ __launch_bounds__(256, 2) void lle_scan_kernel(
    const float* __restrict__ frac,
    const float* __restrict__ exs,
    const float* __restrict__ pos,
    const float* __restrict__ mrate,
    const float* __restrict__ um0,
    const float* __restrict__ msm_min,
    const float* __restrict__ msm_step,
    const float* __restrict__ msm_max,
    float* __restrict__ out)
{
    const int col = blockIdx.x * blockDim.x + threadIdx.x;

    float um = um0[col];

    float fb[PF], eb[PF], pb[PF], mb[PF];

    // warm the ring: symbols 0..PF-1
#pragma unroll
    for (int j = 0; j < PF; ++j) {
        const size_t o = (size_t)j * BATCH + (size_t)col;
        fb[j] = frac[o];
        eb[j] = exs[o];
        pb[j] = pos[o];
        mb[j] = mrate[o];
    }

    // hot loop: symbols 0..N_SYM-PF-1, unconditional prefetch of s+PF
    for (int s0 = 0; s0 < N_SYM - PF; s0 += PF) {
#pragma unroll
        for (int j = 0; j < PF; ++j) {
            const int s = s0 + j;
            const float f = fb[j];
            const float e = eb[j];
            const float p = pb[j];
            const float m = mb[j];

            {   // refill ring slot j with symbol s+PF
                const size_t o = (size_t)(s + PF) * BATCH + (size_t)col;
                fb[j] = frac[o];
                eb[j] = exs[o];
                pb[j] = pos[o];
                mb[j] = mrate[o];
            }

            const float mrl = m * LEV;
            const float us  = um * mrl;                  // unused_size
            const float mps = fabsf(p) + us;             // max_pos_size
            const float adj = fminf((p * f > 0.0f) ? us : mps, 0.0f);
            const float nps = f * (mps - adj);

            float       a  = fabsf(nps);
            const float sg = copysignf(1.0f, nps);
            const float st = msm_step[s];
            a = floorf(a / st) * st;
            a = (a < msm_min[s]) ? 0.0f : a;
            a = fminf(a, msm_max[s]);

            const float res = e * (sg * a) + (1.0f - e) * p;
            __builtin_nontemporal_store(res, &out[(size_t)s * BATCH + (size_t)col]);

            um = (mps - a) / mrl;                        // carry
        }
    }

    // peeled tail: last PF symbols, no prefetch
#pragma unroll
    for (int j = 0; j < PF; ++j) {
        const int s = N_SYM - PF + j;
        const float f = fb[j];
        const float e = eb[j];
        const float p = pb[j];
        const float m = mb[j];

        const float mrl = m * LEV;
        const float us  = um * mrl;
        const float mps = fabsf(p) + us;
        const float adj = fminf((p * f > 0.0f) ? us : mps, 0.0f);
        const float nps = f * (mps - adj);

        float       a  = fabsf(nps);
        const float sg = copysignf(1.0f, nps);
        const float st = msm_step[s];
        a = floorf(a / st) * st;
        a = (a < msm_min[s]) ? 0.0f : a;
        a = fminf(a, msm_max[s]);

        const float res = e * (sg * a) + (1.0f - e) * p;
        __builtin_nontemporal_store(res, &out[(size_t)s * BATCH + (size_t)col]);

        um = (mps - a) / mrl;
    }

    __builtin_nontemporal_store(um, &out[(size_t)N_SYM * BATCH + (size_t)col]);
}

extern "C" void kernel_launch(void* const* d_in, const int* in_sizes, int n_in,
                              void* d_out, int out_size, void* d_ws, size_t ws_size,
                              hipStream_t stream) {
    const float* frac     = (const float*)d_in[0];
    const float* exs      = (const float*)d_in[1];
    const float* pos      = (const float*)d_in[2];
    const float* mrate    = (const float*)d_in[3];
    const float* um0      = (const float*)d_in[4];
    const float* msm_min  = (const float*)d_in[5];
    const float* msm_step = (const float*)d_in[6];
    const float* msm_max  = (const float*)d_in[7];
    float* out = (float*)d_out;

    const int block = 256;
    const int grid  = BATCH / block;   // 512 blocks -> 2 blocks/CU

    hipLaunchKernelGGL(lle_scan_kernel, dim3(grid), dim3(block), 0, stream,
                       frac, exs, pos, mrate, um0, msm_min, msm_step, msm_max,
                       out);
}

// Round 5
// 257.848 us; speedup vs baseline: 1.0775x; 1.0775x over previous
//
#include <hip/hip_runtime.h>
#include <math.h>

#define N_SYM 128
#define BATCH 131072
#define B4    (BATCH / 4)   // row stride in float4 units = 32768
#define LEV   30.0f
#define D     4             // ring depth (iterations of prefetch ahead)

typedef float v4 __attribute__((ext_vector_type(4)));

// 4 columns per thread via float4 (dwordx4) accesses. R0-R2 established the
// bottleneck is NOT scheduling: dword-per-lane loads cap at ~4 KB in flight
// per CU (~1.75 TB/s HBM) regardless of source-level prefetch depth. float4
// requests carry 4x the bytes per outstanding request. 32768 threads =
// 512 waves = 512 blocks x 64 threads -> 2 single-wave blocks/CU, all CUs
// covered. Ring depth 4 -> nominal 16 KB in flight per wave.
__device__ __forceinline__ float step1(float f, float e, float p, float m,
                                       float st, float mn, float mx,
                                       float* um)
{
    const float mrl = m * LEV;
    const float us  = *um * mrl;                // unused_size
    const float mps = fabsf(p) + us;            // max_pos_size
    const float adj = fminf((p * f > 0.0f) ? us : mps, 0.0f);
    const float nps = f * (mps - adj);

    float       a  = fabsf(nps);
    const float sg = copysignf(1.0f, nps);
    a = floorf(a / st) * st;
    a = (a < mn) ? 0.0f : a;
    a = fminf(a, mx);

    *um = (mps - a) / mrl;
    return e * (sg * a) + (1.0f - e) * p;
}

__global__ __launch_bounds__(64) void lle_scan_kernel(
    const float* __restrict__ frac,
    const float* __restrict__ exs,
    const float* __restrict__ pos,
    const float* __restrict__ mrate,
    const float* __restrict__ um0,
    const float* __restrict__ msm_min,
    const float* __restrict__ msm_step,
    const float* __restrict__ msm_max,
    float* __restrict__ out)
{
    const size_t c4 = (size_t)(blockIdx.x * 64 + threadIdx.x); // float4 col idx

    const v4* F = (const v4*)frac;
    const v4* E = (const v4*)exs;
    const v4* P = (const v4*)pos;
    const v4* M = (const v4*)mrate;
    v4*       O = (v4*)out;

    const v4 umv = __builtin_nontemporal_load((const v4*)um0 + c4);
    float um[4] = {umv.x, umv.y, umv.z, umv.w};

    v4 fb[D], eb[D], pb[D], mb[D];

    // warm the ring: symbols 0..D-1
#pragma unroll
    for (int j = 0; j < D; ++j) {
        const size_t o = (size_t)j * B4 + c4;
        fb[j] = __builtin_nontemporal_load(F + o);
        eb[j] = __builtin_nontemporal_load(E + o);
        pb[j] = __builtin_nontemporal_load(P + o);
        mb[j] = __builtin_nontemporal_load(M + o);
    }

    // hot loop: consume s = 0 .. N_SYM-D-1, refill slot with s+D
    for (int s0 = 0; s0 < N_SYM - D; s0 += D) {
#pragma unroll
        for (int j = 0; j < D; ++j) {
            const int s = s0 + j;
            const v4 f = fb[j];
            const v4 e = eb[j];
            const v4 p = pb[j];
            const v4 m = mb[j];

            {   // refill ring slot j with symbol s+D
                const size_t o = (size_t)(s + D) * B4 + c4;
                fb[j] = __builtin_nontemporal_load(F + o);
                eb[j] = __builtin_nontemporal_load(E + o);
                pb[j] = __builtin_nontemporal_load(P + o);
                mb[j] = __builtin_nontemporal_load(M + o);
            }

            const float st = msm_step[s];   // uniform -> s_load
            const float mn = msm_min[s];
            const float mx = msm_max[s];

            v4 r;
            r.x = step1(f.x, e.x, p.x, m.x, st, mn, mx, &um[0]);
            r.y = step1(f.y, e.y, p.y, m.y, st, mn, mx, &um[1]);
            r.z = step1(f.z, e.z, p.z, m.z, st, mn, mx, &um[2]);
            r.w = step1(f.w, e.w, p.w, m.w, st, mn, mx, &um[3]);

            __builtin_nontemporal_store(r, O + (size_t)s * B4 + c4);
        }
    }

    // peeled tail: last D symbols, no refill
#pragma unroll
    for (int j = 0; j < D; ++j) {
        const int s = N_SYM - D + j;
        const v4 f = fb[j];
        const v4 e = eb[j];
        const v4 p = pb[j];
        const v4 m = mb[j];

        const float st = msm_step[s];
        const float mn = msm_min[s];
        const float mx = msm_max[s];

        v4 r;
        r.x = step1(f.x, e.x, p.x, m.x, st, mn, mx, &um[0]);
        r.y = step1(f.y, e.y, p.y, m.y, st, mn, mx, &um[1]);
        r.z = step1(f.z, e.z, p.z, m.z, st, mn, mx, &um[2]);
        r.w = step1(f.w, e.w, p.w, m.w, st, mn, mx, &um[3]);

        __builtin_nontemporal_store(r, O + (size_t)s * B4 + c4);
    }

    v4 umo;
    umo.x = um[0]; umo.y = um[1]; umo.z = um[2]; umo.w = um[3];
    __builtin_nontemporal_store(umo, O + (size_t)N_SYM * B4 + c4);
}

extern "C" void kernel_launch(void* const* d_in, const int* in_sizes, int n_in,
                              void* d_out, int out_size, void* d_ws, size_t ws_size,
                              hipStream_t stream) {
    const float* frac     = (const float*)d_in[0];
    const float* exs      = (const float*)d_in[1];
    const float* pos      = (const float*)d_in[2];
    const float* mrate    = (const float*)d_in[3];
    const float* um0      = (const float*)d_in[4];
    const float* msm_min  = (const float*)d_in[5];
    const float* msm_step = (const float*)d_in[6];
    const float* msm_max  = (const float*)d_in[7];
    float* out = (float*)d_out;

    const int block = 64;
    const int grid  = (BATCH / 4) / block;   // 512 blocks, 1 wave each

    hipLaunchKernelGGL(lle_scan_kernel, dim3(grid), dim3(block), 0, stream,
                       frac, exs, pos, mrate, um0, msm_min, msm_step, msm_max,
                       out);
}